// Round 6
// baseline (52.113 us; speedup 1.0000x reference)
//
#include <hip/hip_runtime.h>

// GradLoss: mean((sobelx(t)-sobelx(o))^2) + mean((sobely(t)-sobely(o))^2)
//         = mean(sobelx(d)^2) + mean(sobely(d)^2), d = t - o   (linearity)
//
// Single custom dispatch + 4B memset (counter reset). Last-finished block
// reduces the per-block partials and writes d_out (agent-scope atomics for
// cross-XCD visibility; no cooperative launch, no same-address atomic storm).
//
// Stage1 geometry: each wave owns a 256-col x 8-row strip (1 float4/lane/row).
//  - ring-4 software pipeline: loads for row i+3 issued while computing row i
//    (~8 dwordx4 in flight/wave, only 32 ring VGPRs; NO launch_bounds cap ->
//    no scratch spills, the R4 mistake).
//  - seam halo column via one divergent load in lanes 0..9 + __shfl broadcast.
//  - separable stencil: row pass s=L+2m+R, dd=R-L; col pass combines 3 rows.
// 4096 waves / 1024 blocks = 16 waves/CU; XCD swizzle for halo L2 locality.

#define BATCH 32
#define HH 512
#define WW 512
#define RW 8                         // output rows per wave
#define NR (RW + 2)                  // rows touched per wave
#define TPB 256
#define NBLK 1024                    // one partial per block
#define WPI 128                      // waves per image (64 y-strips x 2 halves)

__global__ __launch_bounds__(TPB) void sobel_loss_kernel(
    const float* __restrict__ out_img,
    const float* __restrict__ tgt_img,
    float* __restrict__ partials,
    unsigned* __restrict__ counter,
    float* __restrict__ result)
{
    const int tid  = threadIdx.x;
    const int lane = tid & 63;
    // XCD swizzle: 8 XCDs get contiguous 128-block (4-image) chunks
    const int b    = (blockIdx.x & 7) * (NBLK / 8) + (blockIdx.x >> 3);
    const int w    = b * (TPB / 64) + (tid >> 6);   // global wave id, 0..4095
    const int img  = w >> 7;                        // / WPI
    const int r    = w & (WPI - 1);
    const int y0   = (r >> 1) * RW;
    const int xh   = r & 1;
    const int x0   = (xh << 8) + lane * 4;          // this lane's 4 columns

    const size_t base = (size_t)img * HH * WW;
    const float* ob = out_img + base;
    const float* tb = tgt_img + base;
    const int seamcol = xh ? 255 : 256;             // wave-uniform

    // seam halo values for the 10 rows: lanes 0..9 load row (y0-1+lane)
    float seamv = 0.f;
    if (lane < NR) {
        const int g  = y0 - 1 + lane;
        const int gc = min(max(g, 0), HH - 1);
        const float m = ((unsigned)g < (unsigned)HH) ? 1.f : 0.f;
        const size_t ro = (size_t)gc * WW + seamcol;
        seamv = m * (tb[ro] - ob[ro]);
    }

    // ---- ring-4 pipelined loads + separable stencil ----
    float4 ro_[4], rt_[4];
    #define LOAD_ROW(i, slot)                                              \
        do {                                                               \
            const int g_  = y0 - 1 + (i);                                  \
            const int gc_ = min(max(g_, 0), HH - 1);                       \
            const size_t off_ = (size_t)gc_ * WW + x0;                     \
            ro_[slot] = *(const float4*)(ob + off_);                       \
            rt_[slot] = *(const float4*)(tb + off_);                       \
        } while (0)

    #pragma unroll
    for (int i = 0; i < 3; ++i) LOAD_ROW(i, i);

    float hs[3][4], hd[3][4];
    float acc = 0.f;
    #pragma unroll
    for (int i = 0; i < NR; ++i) {
        if (i + 3 < NR) LOAD_ROW(i + 3, (i + 3) & 3);

        const float4 o = ro_[i & 3];
        const float4 t = rt_[i & 3];
        const int   g  = y0 - 1 + i;
        const float m  = ((unsigned)g < (unsigned)HH) ? 1.f : 0.f;
        const float4 d = make_float4(m * (t.x - o.x), m * (t.y - o.y),
                                     m * (t.z - o.z), m * (t.w - o.w));
        const float sv = __shfl(seamv, i, 64);
        float dl = __shfl_up(d.w, 1, 64);
        float dr = __shfl_down(d.x, 1, 64);
        if (lane == 0)  dl = xh ? sv : 0.f;         // left halo (seam or edge)
        if (lane == 63) dr = xh ? 0.f : sv;         // right halo (edge or seam)

        const int cur = i % 3;
        hs[cur][0] = fmaf(2.f, d.x, dl  + d.y);  hd[cur][0] = d.y - dl;
        hs[cur][1] = fmaf(2.f, d.y, d.x + d.z);  hd[cur][1] = d.z - d.x;
        hs[cur][2] = fmaf(2.f, d.z, d.y + d.w);  hd[cur][2] = d.w - d.y;
        hs[cur][3] = fmaf(2.f, d.w, d.z + dr);   hd[cur][3] = dr  - d.z;

        if (i >= 2) {
            const int top = (i - 2) % 3;
            const int mid = (i - 1) % 3;
            #pragma unroll
            for (int j = 0; j < 4; ++j) {
                const float gx = fmaf(2.f, hd[mid][j], hd[top][j] + hd[cur][j]);
                const float gy = hs[top][j] - hs[cur][j];
                acc = fmaf(gx, gx, acc);
                acc = fmaf(gy, gy, acc);
            }
        }
    }
    #undef LOAD_ROW

    // ---- wave reduce -> block reduce -> partial; last block finishes ----
    #pragma unroll
    for (int off = 32; off > 0; off >>= 1)
        acc += __shfl_down(acc, off, 64);

    __shared__ float wsum[TPB / 64];
    __shared__ int   lastflag;
    if (lane == 0) wsum[tid >> 6] = acc;
    __syncthreads();
    if (tid == 0) {
        const float s = wsum[0] + wsum[1] + wsum[2] + wsum[3];
        __hip_atomic_store(&partials[b], s, __ATOMIC_RELAXED,
                           __HIP_MEMORY_SCOPE_AGENT);
        const unsigned old = __hip_atomic_fetch_add(counter, 1u,
                                                    __ATOMIC_ACQ_REL,
                                                    __HIP_MEMORY_SCOPE_AGENT);
        lastflag = (old == NBLK - 1);
    }
    __syncthreads();

    if (lastflag) {
        float s = 0.f;
        #pragma unroll
        for (int k = 0; k < NBLK / TPB; ++k)
            s += __hip_atomic_load(&partials[tid + k * TPB], __ATOMIC_RELAXED,
                                   __HIP_MEMORY_SCOPE_AGENT);
        #pragma unroll
        for (int off = 32; off > 0; off >>= 1)
            s += __shfl_down(s, off, 64);
        if (lane == 0) wsum[tid >> 6] = s;
        __syncthreads();
        if (tid == 0)
            result[0] = (wsum[0] + wsum[1] + wsum[2] + wsum[3])
                      * (1.0f / ((float)BATCH * HH * WW));
    }
}

extern "C" void kernel_launch(void* const* d_in, const int* in_sizes, int n_in,
                              void* d_out, int out_size, void* d_ws, size_t ws_size,
                              hipStream_t stream) {
    (void)in_sizes; (void)n_in; (void)ws_size; (void)out_size;
    const float* out_img = (const float*)d_in[0];   // "output"
    const float* tgt_img = (const float*)d_in[1];   // "target"
    float* partials  = (float*)d_ws;                // NBLK floats
    unsigned* counter = (unsigned*)((char*)d_ws + NBLK * sizeof(float));
    float* res = (float*)d_out;

    hipMemsetAsync(counter, 0, sizeof(unsigned), stream);
    sobel_loss_kernel<<<NBLK, TPB, 0, stream>>>(out_img, tgt_img,
                                                partials, counter, res);
}

// Round 7
// 19.722 us; speedup vs baseline: 2.6424x; 2.6424x over previous
//
#include <hip/hip_runtime.h>

// GradLoss: mean((sobelx(t)-sobelx(o))^2) + mean((sobely(t)-sobely(o))^2)
//         = mean(sobelx(d)^2) + mean(sobely(d)^2), d = t - o   (linearity)
//
// Stage1: per-block tile = full 512-col x 16 output rows (+2 halo rows).
//   Both input slabs staged via __builtin_amdgcn_global_load_lds (16B DMA,
//   zero VGPR cost, ~18 async issues/thread -> huge MLP). Boundary halo rows
//   zeroed in LDS. Compute: 4 waves x 4 rows, ds_read_b128 rows, shuffles for
//   horizontal halo, seam col via LDS, NAMED-variable ring only (no arrays ->
//   no scratch, the R6 bug). One partial per block, plain store.
// Stage2: 1 block reduces 1024 partials -> d_out. No memset, no atomics.

#define BATCH 32
#define HH 512
#define WW 512
#define TR 16                        // output rows per block tile
#define TPB 256
#define NBLK (BATCH * (HH / TR))     // 1024

typedef const __attribute__((address_space(1))) void* gas_ptr;
typedef __attribute__((address_space(3))) void* las_ptr;

__device__ __forceinline__ void async_copy16(const float* g, float* l) {
    __builtin_amdgcn_global_load_lds((gas_ptr)(const void*)g,
                                     (las_ptr)(void*)l, 16, 0, 0);
}

__global__ __launch_bounds__(TPB) void sobel_partial_kernel(
    const float* __restrict__ out_img,
    const float* __restrict__ tgt_img,
    float* __restrict__ partials)
{
    __shared__ float otile[TR + 2][WW];      // 36 KB
    __shared__ float ttile[TR + 2][WW];      // 36 KB
    __shared__ float wsum[TPB / 64];

    const int tid  = threadIdx.x;
    const int lane = tid & 63;
    const int wv   = tid >> 6;               // wave in block, 0..3
    // XCD swizzle: each XCD gets 128 consecutive tiles (4 whole images)
    const int b    = (blockIdx.x & 7) * (NBLK / 8) + (blockIdx.x >> 3);
    const int img  = b >> 5;                 // 32 tiles per image
    const int y0   = (b & 31) * TR;

    const size_t base = (size_t)img * HH * WW;

    // ---- async stage: contiguous slab rows [srcRow0, srcRow0+nrows) ----
    const int top    = (y0 == 0);
    const int bot    = (y0 + TR == HH);
    const int srcRow0 = top ? 0 : y0 - 1;
    const int ldsRow0 = top ? 1 : 0;
    const int nchunk  = (TR + 2 - top - bot) * 2;    // 1KB chunks per array
    const float* osrc = out_img + base + (size_t)srcRow0 * WW;
    const float* tsrc = tgt_img + base + (size_t)srcRow0 * WW;
    float* old = &otile[ldsRow0][0];
    float* tld = &ttile[ldsRow0][0];
    for (int c = wv; c < nchunk; c += 4) {
        const int off = c * 256 + lane * 4;          // floats
        async_copy16(osrc + off, old + off);
        async_copy16(tsrc + off, tld + off);
    }
    // zero never-staged halo rows (image edges). Distinct addresses from the
    // DMA targets, so no ordering hazard before the barrier.
    if (top) {
        if (tid < 128) *(float4*)&otile[0][tid * 4] = make_float4(0, 0, 0, 0);
        else           *(float4*)&ttile[0][(tid - 128) * 4] = make_float4(0, 0, 0, 0);
    }
    if (bot) {
        if (tid < 128) *(float4*)&otile[TR + 1][tid * 4] = make_float4(0, 0, 0, 0);
        else           *(float4*)&ttile[TR + 1][(tid - 128) * 4] = make_float4(0, 0, 0, 0);
    }
    __syncthreads();   // drains vmcnt (gload_lds) + lgkmcnt

    // ---- seam d-values for all 18 rows (one divergent read per wave) ----
    float s255 = 0.f, s256 = 0.f;
    if (lane < TR + 2) {
        s255 = ttile[lane][255] - otile[lane][255];
        s256 = ttile[lane][256] - otile[lane][256];
    }

    // ---- compute: wave wv owns output rows y0+4*wv .. +3 (LDS rows R0..R0+5)
    const int R0 = 4 * wv;
    float acc = 0.f;

#define ROWLOAD(dst, R)                                                     \
    {                                                                       \
        const float4 o4 = *(const float4*)&otile[(R)][cb];                  \
        const float4 t4 = *(const float4*)&ttile[(R)][cb];                  \
        dst = make_float4(t4.x - o4.x, t4.y - o4.y, t4.z - o4.z, t4.w - o4.w); \
    }
#define ROWPASS(hs, hd, d, R)                                               \
    {                                                                       \
        const float svL = __shfl(s255, (R), 64);                            \
        const float svR = __shfl(s256, (R), 64);                            \
        float dl = __shfl_up((d).w, 1, 64);                                 \
        float dr = __shfl_down((d).x, 1, 64);                               \
        if (lane == 0)  dl = h ? svL : 0.f;                                 \
        if (lane == 63) dr = h ? 0.f : svR;                                 \
        hs.x = fmaf(2.f, (d).x, dl + (d).y);      hd.x = (d).y - dl;        \
        hs.y = fmaf(2.f, (d).y, (d).x + (d).z);   hd.y = (d).z - (d).x;     \
        hs.z = fmaf(2.f, (d).z, (d).y + (d).w);   hd.z = (d).w - (d).y;     \
        hs.w = fmaf(2.f, (d).w, (d).z + dr);      hd.w = dr - (d).z;        \
    }
#define ACCUM(hsT, hdT, hsM, hdM, hsB, hdB)                                 \
    {                                                                       \
        float gx, gy;                                                       \
        gx = fmaf(2.f, hdM.x, hdT.x + hdB.x); gy = hsT.x - hsB.x;           \
        acc = fmaf(gx, gx, acc); acc = fmaf(gy, gy, acc);                   \
        gx = fmaf(2.f, hdM.y, hdT.y + hdB.y); gy = hsT.y - hsB.y;           \
        acc = fmaf(gx, gx, acc); acc = fmaf(gy, gy, acc);                   \
        gx = fmaf(2.f, hdM.z, hdT.z + hdB.z); gy = hsT.z - hsB.z;           \
        acc = fmaf(gx, gx, acc); acc = fmaf(gy, gy, acc);                   \
        gx = fmaf(2.f, hdM.w, hdT.w + hdB.w); gy = hsT.w - hsB.w;           \
        acc = fmaf(gx, gx, acc); acc = fmaf(gy, gy, acc);                   \
    }

    #pragma unroll
    for (int h = 0; h < 2; ++h) {
        const int cb = (h << 8) + lane * 4;          // this lane's 4 cols
        float4 d0, d1, d2;
        float4 hs0, hd0, hs1, hd1, hs2, hd2;
        ROWLOAD(d0, R0 + 0); ROWPASS(hs0, hd0, d0, R0 + 0);
        ROWLOAD(d1, R0 + 1); ROWPASS(hs1, hd1, d1, R0 + 1);
        ROWLOAD(d2, R0 + 2); ROWPASS(hs2, hd2, d2, R0 + 2);
        ACCUM(hs0, hd0, hs1, hd1, hs2, hd2);
        ROWLOAD(d0, R0 + 3); ROWPASS(hs0, hd0, d0, R0 + 3);
        ACCUM(hs1, hd1, hs2, hd2, hs0, hd0);
        ROWLOAD(d1, R0 + 4); ROWPASS(hs1, hd1, d1, R0 + 4);
        ACCUM(hs2, hd2, hs0, hd0, hs1, hd1);
        ROWLOAD(d2, R0 + 5); ROWPASS(hs2, hd2, d2, R0 + 5);
        ACCUM(hs0, hd0, hs1, hd1, hs2, hd2);
    }
#undef ROWLOAD
#undef ROWPASS
#undef ACCUM

    // ---- wave reduce -> block reduce -> one plain store ----
    #pragma unroll
    for (int off = 32; off > 0; off >>= 1)
        acc += __shfl_down(acc, off, 64);
    if (lane == 0) wsum[wv] = acc;
    __syncthreads();
    if (tid == 0)
        partials[b] = wsum[0] + wsum[1] + wsum[2] + wsum[3];
}

__global__ __launch_bounds__(TPB) void reduce_partials_kernel(
    const float* __restrict__ partials, float* __restrict__ out)
{
    const int tid = threadIdx.x;
    const float4 v = *(const float4*)(partials + tid * 4);   // 1024 = 256*4
    float s = (v.x + v.y) + (v.z + v.w);
    #pragma unroll
    for (int off = 32; off > 0; off >>= 1)
        s += __shfl_down(s, off, 64);
    __shared__ float wsum[TPB / 64];
    if ((tid & 63) == 0) wsum[tid >> 6] = s;
    __syncthreads();
    if (tid == 0)
        out[0] = (wsum[0] + wsum[1] + wsum[2] + wsum[3])
               * (1.0f / ((float)BATCH * HH * WW));
}

extern "C" void kernel_launch(void* const* d_in, const int* in_sizes, int n_in,
                              void* d_out, int out_size, void* d_ws, size_t ws_size,
                              hipStream_t stream) {
    (void)in_sizes; (void)n_in; (void)ws_size; (void)out_size;
    const float* out_img = (const float*)d_in[0];   // "output"
    const float* tgt_img = (const float*)d_in[1];   // "target"
    float* partials = (float*)d_ws;                 // NBLK floats
    float* res = (float*)d_out;

    sobel_partial_kernel<<<NBLK, TPB, 0, stream>>>(out_img, tgt_img, partials);
    reduce_partials_kernel<<<1, TPB, 0, stream>>>(partials, res);
}